// Round 2
// baseline (296.425 us; speedup 1.0000x reference)
//
#include <hip/hip_runtime.h>

#define NUM_GRAPHS 1024
#define BLOCK 256
#define GROUPS_PER_THREAD 2                              // 4-node groups per thread
#define NODES_PER_BLOCK (BLOCK * GROUPS_PER_THREAD * 4)  // 2048
#define ROWS_PER_THREAD (NODES_PER_BLOCK / BLOCK)        // 8

// ---------------------------------------------------------------------------
// Single fused kernel: segmented |pred-target| sums (sorted batch ids) +
// global force-norm sum; last-finished block performs the finalize reduction.
// ---------------------------------------------------------------------------
__global__ __launch_bounds__(BLOCK) void mae_seg_kernel(
    const float* __restrict__ pred,
    const float* __restrict__ target,
    const int*   __restrict__ batch,
    const float* __restrict__ x,
    float* __restrict__ ws_sum,          // [NUM_GRAPHS]
    float* __restrict__ ws_cnt,          // [NUM_GRAPHS]
    float* __restrict__ ws_force,        // [1]
    unsigned int* __restrict__ ws_ctr,   // [1]
    float* __restrict__ out,
    int n)
{
    __shared__ float ls[NUM_GRAPHS];
    __shared__ float lc[NUM_GRAPHS];
    __shared__ float lf[BLOCK / 64];
    __shared__ int   s_last;

    const int tid      = threadIdx.x;
    const int node0    = blockIdx.x * NODES_PER_BLOCK;
    const int node_end = min(node0 + NODES_PER_BLOCK, n);

    // block's graph-id range (batch is sorted) -> init/flush only this window
    const int b_lo = batch[node0];
    const int b_hi = batch[node_end - 1];
    for (int i = b_lo + tid; i <= b_hi; i += BLOCK) { ls[i] = 0.f; lc[i] = 0.f; }
    __syncthreads();

    // ---- segmented |pred-target| accumulation (run-length per thread) ----
    const float4* p4 = (const float4*)pred;
    const float4* t4 = (const float4*)target;
    const int4*   b4 = (const int4*)batch;

    int   cur_id  = -1;
    float cur_sum = 0.f;
    float cur_cnt = 0.f;

    const int group_base = blockIdx.x * (BLOCK * GROUPS_PER_THREAD);
#pragma unroll
    for (int v = 0; v < GROUPS_PER_THREAD; ++v) {
        const int g    = group_base + v * BLOCK + tid;   // 4-node group index
        const int node = g * 4;
        if (node + 3 < n) {
            float4 pa = p4[g * 3 + 0], pb = p4[g * 3 + 1], pc = p4[g * 3 + 2];
            float4 ta = t4[g * 3 + 0], tb = t4[g * 3 + 1], tc = t4[g * 3 + 2];
            float asum[4];
            asum[0] = fabsf(pa.x - ta.x) + fabsf(pa.y - ta.y) + fabsf(pa.z - ta.z);
            asum[1] = fabsf(pa.w - ta.w) + fabsf(pb.x - tb.x) + fabsf(pb.y - tb.y);
            asum[2] = fabsf(pb.z - tb.z) + fabsf(pb.w - tb.w) + fabsf(pc.x - tc.x);
            asum[3] = fabsf(pc.y - tc.y) + fabsf(pc.z - tc.z) + fabsf(pc.w - tc.w);
            int4 bb = b4[g];
            int bid[4] = {bb.x, bb.y, bb.z, bb.w};
#pragma unroll
            for (int r = 0; r < 4; ++r) {
                if (bid[r] != cur_id) {
                    if (cur_id >= 0) {
                        atomicAdd(&ls[cur_id], cur_sum);
                        atomicAdd(&lc[cur_id], cur_cnt);
                    }
                    cur_id = bid[r]; cur_sum = 0.f; cur_cnt = 0.f;
                }
                cur_sum += asum[r];
                cur_cnt += 1.f;
            }
        } else if (node < n) {
            for (int r = 0; r < 4; ++r) {
                const int nd = node + r;
                if (nd >= n) break;
                float a = fabsf(pred[nd * 3 + 0] - target[nd * 3 + 0])
                        + fabsf(pred[nd * 3 + 1] - target[nd * 3 + 1])
                        + fabsf(pred[nd * 3 + 2] - target[nd * 3 + 2]);
                int b = batch[nd];
                if (b != cur_id) {
                    if (cur_id >= 0) {
                        atomicAdd(&ls[cur_id], cur_sum);
                        atomicAdd(&lc[cur_id], cur_cnt);
                    }
                    cur_id = b; cur_sum = 0.f; cur_cnt = 0.f;
                }
                cur_sum += a;
                cur_cnt += 1.f;
            }
        }
    }
    if (cur_id >= 0) {
        atomicAdd(&ls[cur_id], cur_sum);
        atomicAdd(&lc[cur_id], cur_cnt);
    }

    // ---- force: batched per-row scalar pair loads (no shuffles/divergence).
    // x row r needs floats r*8+3 and r*8+4 (same 64B line). 16 independent
    // dword loads in flight per thread -> latency fully hidden by MLP.
    float f3[ROWS_PER_THREAD], f4[ROWS_PER_THREAD];
#pragma unroll
    for (int v = 0; v < ROWS_PER_THREAD; ++v) {
        const int r = node0 + v * BLOCK + tid;
        const bool ok = (r < n);
        f3[v] = ok ? x[r * 8 + 3] : 0.f;
        f4[v] = ok ? x[r * 8 + 4] : 0.f;
    }
    float s0 = 0.f, s1 = 0.f;
#pragma unroll
    for (int v = 0; v < ROWS_PER_THREAD; v += 2) {
        s0 += sqrtf(f3[v]     * f3[v]     + f4[v]     * f4[v]);
        s1 += sqrtf(f3[v + 1] * f3[v + 1] + f4[v + 1] * f4[v + 1]);
    }
    float fsum = s0 + s1;
#pragma unroll
    for (int off = 32; off > 0; off >>= 1) fsum += __shfl_down(fsum, off, 64);
    if ((tid & 63) == 0) lf[tid >> 6] = fsum;
    __syncthreads();
    if (tid == 0) {
        atomicAdd(ws_force, lf[0] + lf[1] + lf[2] + lf[3]);
    }

    // ---- flush per-block LDS partials (only the touched id window) ----
    for (int i = b_lo + tid; i <= b_hi; i += BLOCK) {
        float c = lc[i];
        if (c != 0.f) {
            atomicAdd(&ws_sum[i], ls[i]);
            atomicAdd(&ws_cnt[i], c);
        }
    }

    // ---- completion handshake; last block finalizes ----
    __threadfence();
    __syncthreads();
    if (tid == 0) {
        unsigned prev = atomicAdd(ws_ctr, 1u);
        s_last = (prev == gridDim.x - 1) ? 1 : 0;
    }
    __syncthreads();
    if (!s_last) return;

    // last block: reduce graph_mae over all graphs; device-scope atomic loads
    // guarantee cross-XCD visibility of other blocks' atomics.
    float part = 0.f;
    for (int i = tid; i < NUM_GRAPHS; i += BLOCK) {
        float s = __hip_atomic_load(&ws_sum[i], __ATOMIC_RELAXED, __HIP_MEMORY_SCOPE_AGENT);
        float c = __hip_atomic_load(&ws_cnt[i], __ATOMIC_RELAXED, __HIP_MEMORY_SCOPE_AGENT);
        part += s / (fmaxf(c, 1.0f) * 3.0f);
    }
#pragma unroll
    for (int off = 32; off > 0; off >>= 1) part += __shfl_down(part, off, 64);
    __syncthreads();                       // lf reuse safe
    if ((tid & 63) == 0) lf[tid >> 6] = part;
    __syncthreads();
    if (tid == 0) {
        float tot   = lf[0] + lf[1] + lf[2] + lf[3];
        float force = __hip_atomic_load(ws_force, __ATOMIC_RELAXED, __HIP_MEMORY_SCOPE_AGENT);
        float scale = fmaxf(force, 0.1f);
        out[0] = (tot / (float)NUM_GRAPHS) * scale * 100.0f;
    }
}

extern "C" void kernel_launch(void* const* d_in, const int* in_sizes, int n_in,
                              void* d_out, int out_size, void* d_ws, size_t ws_size,
                              hipStream_t stream) {
    const float* pred   = (const float*)d_in[0];
    const float* target = (const float*)d_in[1];
    const int*   batch  = (const int*)d_in[2];
    const float* x      = (const float*)d_in[3];
    float* out = (float*)d_out;

    const int n = in_sizes[2];                 // N nodes (batch vector length)

    float* ws_sum         = (float*)d_ws;      // [1024]
    float* ws_cnt         = ws_sum + NUM_GRAPHS;
    float* ws_force       = ws_cnt + NUM_GRAPHS;          // [1]
    unsigned int* ws_ctr  = (unsigned int*)(ws_force + 1);// [1]

    hipMemsetAsync(d_ws, 0, (2 * NUM_GRAPHS + 2) * sizeof(float), stream);

    const int blocks = (n + NODES_PER_BLOCK - 1) / NODES_PER_BLOCK;
    mae_seg_kernel<<<blocks, BLOCK, 0, stream>>>(pred, target, batch, x,
                                                 ws_sum, ws_cnt, ws_force, ws_ctr,
                                                 out, n);
}

// Round 3
// 58.710 us; speedup vs baseline: 5.0490x; 5.0490x over previous
//
#include <hip/hip_runtime.h>

#define NUM_GRAPHS 1024
#define BLOCK 256
#define GROUPS_PER_THREAD 2                              // 4-node groups per thread
#define NODES_PER_BLOCK (BLOCK * GROUPS_PER_THREAD * 4)  // 2048

// ---------------------------------------------------------------------------
// Kernel 1: segmented |pred-target| sums (sorted batch ids) + force-norm sum.
// All loads fully coalesced float4/int4; x pair (f3,f4) recovered via
// shfl_xor(1); 8 loads batched in registers for memory-level parallelism.
// ---------------------------------------------------------------------------
__global__ __launch_bounds__(BLOCK) void mae_seg_kernel(
    const float* __restrict__ pred,
    const float* __restrict__ target,
    const int*   __restrict__ batch,
    const float* __restrict__ x,
    float* __restrict__ ws_sum,    // [NUM_GRAPHS]
    float* __restrict__ ws_cnt,    // [NUM_GRAPHS]
    float* __restrict__ ws_force,  // [1]
    int n)
{
    __shared__ float ls[NUM_GRAPHS];
    __shared__ float lc[NUM_GRAPHS];
    __shared__ float lf[BLOCK / 64];

    const int tid      = threadIdx.x;
    const int node0    = blockIdx.x * NODES_PER_BLOCK;
    const int node_end = min(node0 + NODES_PER_BLOCK, n);

    // block's graph-id window (batch sorted) -> init/flush only this range
    const int b_lo = batch[node0];
    const int b_hi = batch[node_end - 1];
    for (int i = b_lo + tid; i <= b_hi; i += BLOCK) { ls[i] = 0.f; lc[i] = 0.f; }
    __syncthreads();

    // ---- segmented |pred-target| accumulation (run-length per thread) ----
    const float4* p4 = (const float4*)pred;
    const float4* t4 = (const float4*)target;
    const int4*   b4 = (const int4*)batch;

    int   cur_id  = -1;
    float cur_sum = 0.f;
    float cur_cnt = 0.f;

    const int group_base = blockIdx.x * (BLOCK * GROUPS_PER_THREAD);
#pragma unroll
    for (int v = 0; v < GROUPS_PER_THREAD; ++v) {
        const int g    = group_base + v * BLOCK + tid;   // 4-node group index
        const int node = g * 4;
        if (node + 3 < n) {
            float4 pa = p4[g * 3 + 0], pb = p4[g * 3 + 1], pc = p4[g * 3 + 2];
            float4 ta = t4[g * 3 + 0], tb = t4[g * 3 + 1], tc = t4[g * 3 + 2];
            float asum[4];
            asum[0] = fabsf(pa.x - ta.x) + fabsf(pa.y - ta.y) + fabsf(pa.z - ta.z);
            asum[1] = fabsf(pa.w - ta.w) + fabsf(pb.x - tb.x) + fabsf(pb.y - tb.y);
            asum[2] = fabsf(pb.z - tb.z) + fabsf(pb.w - tb.w) + fabsf(pc.x - tc.x);
            asum[3] = fabsf(pc.y - tc.y) + fabsf(pc.z - tc.z) + fabsf(pc.w - tc.w);
            int4 bb = b4[g];
            int bid[4] = {bb.x, bb.y, bb.z, bb.w};
#pragma unroll
            for (int r = 0; r < 4; ++r) {
                if (bid[r] != cur_id) {
                    if (cur_id >= 0) {
                        atomicAdd(&ls[cur_id], cur_sum);
                        atomicAdd(&lc[cur_id], cur_cnt);
                    }
                    cur_id = bid[r]; cur_sum = 0.f; cur_cnt = 0.f;
                }
                cur_sum += asum[r];
                cur_cnt += 1.f;
            }
        } else if (node < n) {
            for (int r = 0; r < 4; ++r) {
                const int nd = node + r;
                if (nd >= n) break;
                float a = fabsf(pred[nd * 3 + 0] - target[nd * 3 + 0])
                        + fabsf(pred[nd * 3 + 1] - target[nd * 3 + 1])
                        + fabsf(pred[nd * 3 + 2] - target[nd * 3 + 2]);
                int b = batch[nd];
                if (b != cur_id) {
                    if (cur_id >= 0) {
                        atomicAdd(&ls[cur_id], cur_sum);
                        atomicAdd(&lc[cur_id], cur_cnt);
                    }
                    cur_id = b; cur_sum = 0.f; cur_cnt = 0.f;
                }
                cur_sum += a;
                cur_cnt += 1.f;
            }
        }
    }
    if (cur_id >= 0) {
        atomicAdd(&ls[cur_id], cur_sum);
        atomicAdd(&lc[cur_id], cur_cnt);
    }

    // ---- force: coalesced float4 over flat x, pair via shfl_xor(1).
    // Batched 8 loads -> register array -> consume, for 8-deep MLP.
    const float4* x4 = (const float4*)x;
    const int nx4   = n * 2;                     // total float4s in x
    const int xbase = blockIdx.x * (NODES_PER_BLOCK * 2);
    float fsum = 0.f;
#pragma unroll
    for (int half = 0; half < 2; ++half) {
        const int i0 = xbase + half * 8 * BLOCK;
        float4 xv[8];
#pragma unroll
        for (int v = 0; v < 8; ++v) {
            const int idx = i0 + v * BLOCK + tid;
            xv[v] = (idx < nx4) ? x4[idx] : make_float4(0.f, 0.f, 0.f, 0.f);
        }
#pragma unroll
        for (int v = 0; v < 8; ++v) {
            const int idx   = i0 + v * BLOCK + tid;
            const float val = (tid & 1) ? xv[v].x : xv[v].w;
            const float oth = __shfl_xor(val, 1, 64);
            if (((tid & 1) == 0) && idx < nx4)
                fsum += sqrtf(val * val + oth * oth);
        }
    }
#pragma unroll
    for (int off = 32; off > 0; off >>= 1) fsum += __shfl_down(fsum, off, 64);
    if ((tid & 63) == 0) lf[tid >> 6] = fsum;
    __syncthreads();
    if (tid == 0) {
        atomicAdd(ws_force, lf[0] + lf[1] + lf[2] + lf[3]);
    }

    // ---- flush per-block LDS partials (only the touched id window) ----
    for (int i = b_lo + tid; i <= b_hi; i += BLOCK) {
        float c = lc[i];
        if (c != 0.f) {
            atomicAdd(&ws_sum[i], ls[i]);
            atomicAdd(&ws_cnt[i], c);
        }
    }
}

// ---------------------------------------------------------------------------
// Kernel 2: finalize — mean over graphs of seg_sum/(max(cnt,1)*3), scale.
// ---------------------------------------------------------------------------
__global__ __launch_bounds__(NUM_GRAPHS) void finalize_kernel(
    const float* __restrict__ ws_sum,
    const float* __restrict__ ws_cnt,
    const float* __restrict__ ws_force,
    float* __restrict__ out)
{
    __shared__ float red[NUM_GRAPHS];
    const int t = threadIdx.x;
    red[t] = ws_sum[t] / (fmaxf(ws_cnt[t], 1.0f) * 3.0f);
    __syncthreads();
    for (int s = NUM_GRAPHS / 2; s > 0; s >>= 1) {
        if (t < s) red[t] += red[t + s];
        __syncthreads();
    }
    if (t == 0) {
        const float scale = fmaxf(ws_force[0], 0.1f);
        out[0] = (red[0] / (float)NUM_GRAPHS) * scale * 100.0f;
    }
}

extern "C" void kernel_launch(void* const* d_in, const int* in_sizes, int n_in,
                              void* d_out, int out_size, void* d_ws, size_t ws_size,
                              hipStream_t stream) {
    const float* pred   = (const float*)d_in[0];
    const float* target = (const float*)d_in[1];
    const int*   batch  = (const int*)d_in[2];
    const float* x      = (const float*)d_in[3];
    float* out = (float*)d_out;

    const int n = in_sizes[2];                  // N nodes (batch vector length)

    float* ws_sum   = (float*)d_ws;             // [1024]
    float* ws_cnt   = ws_sum + NUM_GRAPHS;      // [1024]
    float* ws_force = ws_cnt + NUM_GRAPHS;      // [1]

    hipMemsetAsync(d_ws, 0, (2 * NUM_GRAPHS + 1) * sizeof(float), stream);

    const int blocks = (n + NODES_PER_BLOCK - 1) / NODES_PER_BLOCK;
    mae_seg_kernel<<<blocks, BLOCK, 0, stream>>>(pred, target, batch, x,
                                                 ws_sum, ws_cnt, ws_force, n);
    finalize_kernel<<<1, NUM_GRAPHS, 0, stream>>>(ws_sum, ws_cnt, ws_force, out);
}

// Round 4
// 58.524 us; speedup vs baseline: 5.0651x; 1.0032x over previous
//
#include <hip/hip_runtime.h>

#define NUM_GRAPHS 1024
#define BLOCK 256
#define GROUPS_PER_THREAD 2                              // 4-node groups per thread
#define NODES_PER_BLOCK (BLOCK * GROUPS_PER_THREAD * 4)  // 2048

// ---------------------------------------------------------------------------
// Kernel 1: segmented |pred-target| sums (sorted batch ids) + force-norm sum.
// Fast path (full blocks, 1953/1954): unguarded coalesced float4/int4 loads,
// wave-aggregated LDS atomics (1 atomic pair per uniform wave).
// ---------------------------------------------------------------------------
__global__ __launch_bounds__(BLOCK, 8) void mae_seg_kernel(
    const float* __restrict__ pred,
    const float* __restrict__ target,
    const int*   __restrict__ batch,
    const float* __restrict__ x,
    float* __restrict__ ws_sum,    // [NUM_GRAPHS]
    float* __restrict__ ws_cnt,    // [NUM_GRAPHS]
    float* __restrict__ ws_force,  // [1]
    int n)
{
    __shared__ float ls[NUM_GRAPHS];
    __shared__ float lc[NUM_GRAPHS];
    __shared__ float lf[BLOCK / 64];

    const int tid      = threadIdx.x;
    const int node0    = blockIdx.x * NODES_PER_BLOCK;
    const int node_end = min(node0 + NODES_PER_BLOCK, n);
    const bool full    = (node0 + NODES_PER_BLOCK) <= n;

    // block's graph-id window (batch sorted) -> init/flush only this range
    const int b_lo = batch[node0];
    const int b_hi = batch[node_end - 1];
    for (int i = b_lo + tid; i <= b_hi; i += BLOCK) { ls[i] = 0.f; lc[i] = 0.f; }
    __syncthreads();

    // ---- segmented |pred-target| accumulation (run-length per thread) ----
    const float4* p4 = (const float4*)pred;
    const float4* t4 = (const float4*)target;
    const int4*   b4 = (const int4*)batch;

    int   cur_id  = -1;
    float cur_sum = 0.f;
    float cur_cnt = 0.f;

    const int group_base = blockIdx.x * (BLOCK * GROUPS_PER_THREAD);
    if (full) {
#pragma unroll
        for (int v = 0; v < GROUPS_PER_THREAD; ++v) {
            const int g = group_base + v * BLOCK + tid;   // 4-node group index
            float4 pa = p4[g * 3 + 0], pb = p4[g * 3 + 1], pc = p4[g * 3 + 2];
            float4 ta = t4[g * 3 + 0], tb = t4[g * 3 + 1], tc = t4[g * 3 + 2];
            int4   bb = b4[g];
            float asum[4];
            asum[0] = fabsf(pa.x - ta.x) + fabsf(pa.y - ta.y) + fabsf(pa.z - ta.z);
            asum[1] = fabsf(pa.w - ta.w) + fabsf(pb.x - tb.x) + fabsf(pb.y - tb.y);
            asum[2] = fabsf(pb.z - tb.z) + fabsf(pb.w - tb.w) + fabsf(pc.x - tc.x);
            asum[3] = fabsf(pc.y - tc.y) + fabsf(pc.z - tc.z) + fabsf(pc.w - tc.w);
            int bid[4] = {bb.x, bb.y, bb.z, bb.w};
#pragma unroll
            for (int r = 0; r < 4; ++r) {
                if (bid[r] != cur_id) {
                    if (cur_id >= 0) {          // mid-thread run flush (rare)
                        atomicAdd(&ls[cur_id], cur_sum);
                        atomicAdd(&lc[cur_id], cur_cnt);
                    }
                    cur_id = bid[r]; cur_sum = 0.f; cur_cnt = 0.f;
                }
                cur_sum += asum[r];
                cur_cnt += 1.f;
            }
        }
    } else {
        for (int v = 0; v < GROUPS_PER_THREAD; ++v) {
            const int node = (group_base + v * BLOCK + tid) * 4;
            for (int r = 0; r < 4; ++r) {
                const int nd = node + r;
                if (nd >= n) break;
                float a = fabsf(pred[nd * 3 + 0] - target[nd * 3 + 0])
                        + fabsf(pred[nd * 3 + 1] - target[nd * 3 + 1])
                        + fabsf(pred[nd * 3 + 2] - target[nd * 3 + 2]);
                int b = batch[nd];
                if (b != cur_id) {
                    if (cur_id >= 0) {
                        atomicAdd(&ls[cur_id], cur_sum);
                        atomicAdd(&lc[cur_id], cur_cnt);
                    }
                    cur_id = b; cur_sum = 0.f; cur_cnt = 0.f;
                }
                cur_sum += a;
                cur_cnt += 1.f;
            }
        }
    }

    // ---- wave-aggregated flush of the final run ----
    {
        const int id0 = __shfl(cur_id, 0, 64);
        if (__all(cur_id == id0)) {
            // uniform wave (common: runs ~3900 nodes): one atomic pair
            float s = cur_sum, c = cur_cnt;
#pragma unroll
            for (int off = 32; off > 0; off >>= 1) {
                s += __shfl_xor(s, off, 64);
                c += __shfl_xor(c, off, 64);
            }
            if ((tid & 63) == 0 && id0 >= 0) {
                atomicAdd(&ls[id0], s);
                atomicAdd(&lc[id0], c);
            }
        } else if (cur_id >= 0) {
            atomicAdd(&ls[cur_id], cur_sum);
            atomicAdd(&lc[cur_id], cur_cnt);
        }
    }

    // ---- force: coalesced float4 over flat x, pair via shfl_xor(1).
    // Norm is symmetric under the swap -> all lanes accumulate, halve once.
    const float4* x4 = (const float4*)x;
    const int xbase = blockIdx.x * (NODES_PER_BLOCK * 2);
    float fsum = 0.f;
    if (full) {
#pragma unroll
        for (int half = 0; half < 2; ++half) {
            const int i0 = xbase + half * 8 * BLOCK;
            float4 xv[8];
#pragma unroll
            for (int v = 0; v < 8; ++v) xv[v] = x4[i0 + v * BLOCK + tid];
#pragma unroll
            for (int v = 0; v < 8; ++v) {
                const float val = (tid & 1) ? xv[v].x : xv[v].w;
                const float oth = __shfl_xor(val, 1, 64);
                fsum += sqrtf(val * val + oth * oth);
            }
        }
    } else {
        const int nx4 = n * 2;
#pragma unroll
        for (int v = 0; v < 16; ++v) {
            const int idx = xbase + v * BLOCK + tid;
            float val = 0.f;
            if (idx < nx4) {
                float4 xv = x4[idx];
                val = (tid & 1) ? xv.x : xv.w;
            }
            const float oth = __shfl_xor(val, 1, 64);
            fsum += sqrtf(val * val + oth * oth);
        }
    }
    fsum *= 0.5f;                       // each row norm counted by both lanes
#pragma unroll
    for (int off = 32; off > 0; off >>= 1) fsum += __shfl_down(fsum, off, 64);
    if ((tid & 63) == 0) lf[tid >> 6] = fsum;
    __syncthreads();
    if (tid == 0) {
        atomicAdd(ws_force, lf[0] + lf[1] + lf[2] + lf[3]);
    }

    // ---- flush per-block LDS partials (only the touched id window) ----
    // (the __syncthreads above guarantees all waves' LDS atomics completed)
    for (int i = b_lo + tid; i <= b_hi; i += BLOCK) {
        float c = lc[i];
        if (c != 0.f) {
            atomicAdd(&ws_sum[i], ls[i]);
            atomicAdd(&ws_cnt[i], c);
        }
    }
}

// ---------------------------------------------------------------------------
// Kernel 2: finalize — mean over graphs of seg_sum/(max(cnt,1)*3), scale.
// ---------------------------------------------------------------------------
__global__ __launch_bounds__(NUM_GRAPHS) void finalize_kernel(
    const float* __restrict__ ws_sum,
    const float* __restrict__ ws_cnt,
    const float* __restrict__ ws_force,
    float* __restrict__ out)
{
    __shared__ float red[NUM_GRAPHS];
    const int t = threadIdx.x;
    red[t] = ws_sum[t] / (fmaxf(ws_cnt[t], 1.0f) * 3.0f);
    __syncthreads();
    for (int s = NUM_GRAPHS / 2; s > 0; s >>= 1) {
        if (t < s) red[t] += red[t + s];
        __syncthreads();
    }
    if (t == 0) {
        const float scale = fmaxf(ws_force[0], 0.1f);
        out[0] = (red[0] / (float)NUM_GRAPHS) * scale * 100.0f;
    }
}

extern "C" void kernel_launch(void* const* d_in, const int* in_sizes, int n_in,
                              void* d_out, int out_size, void* d_ws, size_t ws_size,
                              hipStream_t stream) {
    const float* pred   = (const float*)d_in[0];
    const float* target = (const float*)d_in[1];
    const int*   batch  = (const int*)d_in[2];
    const float* x      = (const float*)d_in[3];
    float* out = (float*)d_out;

    const int n = in_sizes[2];                  // N nodes (batch vector length)

    float* ws_sum   = (float*)d_ws;             // [1024]
    float* ws_cnt   = ws_sum + NUM_GRAPHS;      // [1024]
    float* ws_force = ws_cnt + NUM_GRAPHS;      // [1]

    hipMemsetAsync(d_ws, 0, (2 * NUM_GRAPHS + 1) * sizeof(float), stream);

    const int blocks = (n + NODES_PER_BLOCK - 1) / NODES_PER_BLOCK;
    mae_seg_kernel<<<blocks, BLOCK, 0, stream>>>(pred, target, batch, x,
                                                 ws_sum, ws_cnt, ws_force, n);
    finalize_kernel<<<1, NUM_GRAPHS, 0, stream>>>(ws_sum, ws_cnt, ws_force, out);
}

// Round 5
// 56.267 us; speedup vs baseline: 5.2682x; 1.0401x over previous
//
#include <hip/hip_runtime.h>

#define NUM_GRAPHS 1024
#define BLOCK 256
#define GROUPS_PER_THREAD 2                              // 4-node groups per thread
#define NODES_PER_BLOCK (BLOCK * GROUPS_PER_THREAD * 4)  // 2048

// ---------------------------------------------------------------------------
// Kernel 1: segmented |pred-target| sums (sorted batch ids) + force-norm sum.
// Latency-bound fix: explicit register-array load batching (14 loads in
// flight in seg phase, 8 in x phase) under __launch_bounds__(256,4).
// ---------------------------------------------------------------------------
__global__ __launch_bounds__(BLOCK, 4) void mae_seg_kernel(
    const float* __restrict__ pred,
    const float* __restrict__ target,
    const int*   __restrict__ batch,
    const float* __restrict__ x,
    float* __restrict__ ws_sum,    // [NUM_GRAPHS]
    float* __restrict__ ws_cnt,    // [NUM_GRAPHS]
    float* __restrict__ ws_force,  // [1]
    int n)
{
    __shared__ float ls[NUM_GRAPHS];
    __shared__ float lc[NUM_GRAPHS];
    __shared__ float lf[BLOCK / 64];

    const int tid      = threadIdx.x;
    const int node0    = blockIdx.x * NODES_PER_BLOCK;
    const int node_end = min(node0 + NODES_PER_BLOCK, n);
    const bool full    = (node0 + NODES_PER_BLOCK) <= n;

    // block's graph-id window (batch sorted) -> init/flush only this range
    const int b_lo = batch[node0];
    const int b_hi = batch[node_end - 1];
    for (int i = b_lo + tid; i <= b_hi; i += BLOCK) { ls[i] = 0.f; lc[i] = 0.f; }
    __syncthreads();

    const float4* p4 = (const float4*)pred;
    const float4* t4 = (const float4*)target;
    const int4*   b4 = (const int4*)batch;

    int   cur_id  = -1;
    float cur_sum = 0.f;
    float cur_cnt = 0.f;

    const int group_base = blockIdx.x * (BLOCK * GROUPS_PER_THREAD);
    if (full) {
        // ---- issue ALL 14 seg-phase loads into register arrays first ----
        float4 P[2][3], T[2][3];
        int4   B[2];
#pragma unroll
        for (int v = 0; v < GROUPS_PER_THREAD; ++v) {
            const int g = group_base + v * BLOCK + tid;
            P[v][0] = p4[g * 3 + 0]; P[v][1] = p4[g * 3 + 1]; P[v][2] = p4[g * 3 + 2];
            T[v][0] = t4[g * 3 + 0]; T[v][1] = t4[g * 3 + 1]; T[v][2] = t4[g * 3 + 2];
            B[v]    = b4[g];
        }
        // ---- consume ----
#pragma unroll
        for (int v = 0; v < GROUPS_PER_THREAD; ++v) {
            float4 pa = P[v][0], pb = P[v][1], pc = P[v][2];
            float4 ta = T[v][0], tb = T[v][1], tc = T[v][2];
            float asum[4];
            asum[0] = fabsf(pa.x - ta.x) + fabsf(pa.y - ta.y) + fabsf(pa.z - ta.z);
            asum[1] = fabsf(pa.w - ta.w) + fabsf(pb.x - tb.x) + fabsf(pb.y - tb.y);
            asum[2] = fabsf(pb.z - tb.z) + fabsf(pb.w - tb.w) + fabsf(pc.x - tc.x);
            asum[3] = fabsf(pc.y - tc.y) + fabsf(pc.z - tc.z) + fabsf(pc.w - tc.w);
            int bid[4] = {B[v].x, B[v].y, B[v].z, B[v].w};
            if (bid[0] == cur_id && bid[3] == cur_id) {
                // fast path: whole group in current run (runs ~3900 nodes)
                cur_sum += asum[0] + asum[1] + asum[2] + asum[3];
                cur_cnt += 4.f;
            } else {
#pragma unroll
                for (int r = 0; r < 4; ++r) {
                    if (bid[r] != cur_id) {
                        if (cur_id >= 0) {
                            atomicAdd(&ls[cur_id], cur_sum);
                            atomicAdd(&lc[cur_id], cur_cnt);
                        }
                        cur_id = bid[r]; cur_sum = 0.f; cur_cnt = 0.f;
                    }
                    cur_sum += asum[r];
                    cur_cnt += 1.f;
                }
            }
        }
    } else {
        for (int v = 0; v < GROUPS_PER_THREAD; ++v) {
            const int node = (group_base + v * BLOCK + tid) * 4;
            for (int r = 0; r < 4; ++r) {
                const int nd = node + r;
                if (nd >= n) break;
                float a = fabsf(pred[nd * 3 + 0] - target[nd * 3 + 0])
                        + fabsf(pred[nd * 3 + 1] - target[nd * 3 + 1])
                        + fabsf(pred[nd * 3 + 2] - target[nd * 3 + 2]);
                int b = batch[nd];
                if (b != cur_id) {
                    if (cur_id >= 0) {
                        atomicAdd(&ls[cur_id], cur_sum);
                        atomicAdd(&lc[cur_id], cur_cnt);
                    }
                    cur_id = b; cur_sum = 0.f; cur_cnt = 0.f;
                }
                cur_sum += a;
                cur_cnt += 1.f;
            }
        }
    }

    // ---- wave-aggregated flush of the final run ----
    {
        const int id0 = __shfl(cur_id, 0, 64);
        if (__all(cur_id == id0)) {
            float s = cur_sum, c = cur_cnt;
#pragma unroll
            for (int off = 32; off > 0; off >>= 1) {
                s += __shfl_xor(s, off, 64);
                c += __shfl_xor(c, off, 64);
            }
            if ((tid & 63) == 0 && id0 >= 0) {
                atomicAdd(&ls[id0], s);
                atomicAdd(&lc[id0], c);
            }
        } else if (cur_id >= 0) {
            atomicAdd(&ls[cur_id], cur_sum);
            atomicAdd(&lc[cur_id], cur_cnt);
        }
    }

    // ---- force: coalesced float4 over flat x, pair via shfl_xor(1).
    // Norm symmetric under swap -> all lanes accumulate, halve once.
    const float4* x4 = (const float4*)x;
    const int xbase = blockIdx.x * (NODES_PER_BLOCK * 2);
    float fsum = 0.f;
    if (full) {
#pragma unroll
        for (int half = 0; half < 2; ++half) {
            const int i0 = xbase + half * 8 * BLOCK;
            float4 xv[8];
#pragma unroll
            for (int v = 0; v < 8; ++v) xv[v] = x4[i0 + v * BLOCK + tid];
#pragma unroll
            for (int v = 0; v < 8; ++v) {
                const float val = (tid & 1) ? xv[v].x : xv[v].w;
                const float oth = __shfl_xor(val, 1, 64);
                fsum += sqrtf(val * val + oth * oth);
            }
        }
    } else {
        const int nx4 = n * 2;
#pragma unroll
        for (int v = 0; v < 16; ++v) {
            const int idx = xbase + v * BLOCK + tid;
            float val = 0.f;
            if (idx < nx4) {
                float4 xv = x4[idx];
                val = (tid & 1) ? xv.x : xv.w;
            }
            const float oth = __shfl_xor(val, 1, 64);
            fsum += sqrtf(val * val + oth * oth);
        }
    }
    fsum *= 0.5f;
#pragma unroll
    for (int off = 32; off > 0; off >>= 1) fsum += __shfl_down(fsum, off, 64);
    if ((tid & 63) == 0) lf[tid >> 6] = fsum;
    __syncthreads();
    if (tid == 0) {
        atomicAdd(ws_force, lf[0] + lf[1] + lf[2] + lf[3]);
    }

    // ---- flush per-block LDS partials (only the touched id window) ----
    for (int i = b_lo + tid; i <= b_hi; i += BLOCK) {
        float c = lc[i];
        if (c != 0.f) {
            atomicAdd(&ws_sum[i], ls[i]);
            atomicAdd(&ws_cnt[i], c);
        }
    }
}

// ---------------------------------------------------------------------------
// Kernel 2: finalize — mean over graphs of seg_sum/(max(cnt,1)*3), scale.
// ---------------------------------------------------------------------------
__global__ __launch_bounds__(NUM_GRAPHS) void finalize_kernel(
    const float* __restrict__ ws_sum,
    const float* __restrict__ ws_cnt,
    const float* __restrict__ ws_force,
    float* __restrict__ out)
{
    __shared__ float red[NUM_GRAPHS];
    const int t = threadIdx.x;
    red[t] = ws_sum[t] / (fmaxf(ws_cnt[t], 1.0f) * 3.0f);
    __syncthreads();
    for (int s = NUM_GRAPHS / 2; s > 0; s >>= 1) {
        if (t < s) red[t] += red[t + s];
        __syncthreads();
    }
    if (t == 0) {
        const float scale = fmaxf(ws_force[0], 0.1f);
        out[0] = (red[0] / (float)NUM_GRAPHS) * scale * 100.0f;
    }
}

extern "C" void kernel_launch(void* const* d_in, const int* in_sizes, int n_in,
                              void* d_out, int out_size, void* d_ws, size_t ws_size,
                              hipStream_t stream) {
    const float* pred   = (const float*)d_in[0];
    const float* target = (const float*)d_in[1];
    const int*   batch  = (const int*)d_in[2];
    const float* x      = (const float*)d_in[3];
    float* out = (float*)d_out;

    const int n = in_sizes[2];                  // N nodes (batch vector length)

    float* ws_sum   = (float*)d_ws;             // [1024]
    float* ws_cnt   = ws_sum + NUM_GRAPHS;      // [1024]
    float* ws_force = ws_cnt + NUM_GRAPHS;      // [1]

    hipMemsetAsync(d_ws, 0, (2 * NUM_GRAPHS + 1) * sizeof(float), stream);

    const int blocks = (n + NODES_PER_BLOCK - 1) / NODES_PER_BLOCK;
    mae_seg_kernel<<<blocks, BLOCK, 0, stream>>>(pred, target, batch, x,
                                                 ws_sum, ws_cnt, ws_force, n);
    finalize_kernel<<<1, NUM_GRAPHS, 0, stream>>>(ws_sum, ws_cnt, ws_force, out);
}

// Round 6
// 51.234 us; speedup vs baseline: 5.7857x; 1.0982x over previous
//
#include <hip/hip_runtime.h>

#define NUM_GRAPHS 1024
#define BLOCK 256
#define TILE_NODES 1024                       // 4 nodes per thread per tile
#define TILES_PER_BLOCK 4
#define CHUNK (TILE_NODES * TILES_PER_BLOCK)  // 4096 contiguous nodes per block

// ---------------------------------------------------------------------------
// Kernel 1: segmented |pred-target| sums (sorted batch ids) + force-norm sum.
// Persistent chunked blocks; explicit 2-deep double-buffered load pipeline
// (LOAD(t+1) issued before CONSUME(t)) -> ~15-30 loads in flight per wave,
// no barrier in the main loop to drain vmcnt.
// ---------------------------------------------------------------------------
__global__ __launch_bounds__(BLOCK, 2) void mae_seg_kernel(
    const float* __restrict__ pred,
    const float* __restrict__ target,
    const int*   __restrict__ batch,
    const float* __restrict__ x,
    float* __restrict__ ws_sum,    // [NUM_GRAPHS]
    float* __restrict__ ws_cnt,    // [NUM_GRAPHS]
    float* __restrict__ ws_force,  // [1]
    int n)
{
    __shared__ float ls[NUM_GRAPHS];
    __shared__ float lc[NUM_GRAPHS];
    __shared__ float lf[BLOCK / 64];

    const int tid      = threadIdx.x;
    const int node0    = blockIdx.x * CHUNK;
    if (node0 >= n) return;                    // safety (grid sized from n)
    const int node_end = min(node0 + CHUNK, n);

    // block's graph-id window (batch sorted) -> init/flush only this range
    const int b_lo = batch[node0];
    const int b_hi = batch[node_end - 1];
    for (int i = b_lo + tid; i <= b_hi; i += BLOCK) { ls[i] = 0.f; lc[i] = 0.f; }
    __syncthreads();

    const float4* p4 = (const float4*)pred;
    const float4* t4 = (const float4*)target;
    const int4*   b4 = (const int4*)batch;
    const float4* x4 = (const float4*)x;

    int   cur_id  = -1;
    float cur_sum = 0.f;
    float cur_cnt = 0.f;
    float fsum    = 0.f;

    // number of FULL tiles in this block's chunk (block-uniform)
    int ft = (node_end - node0) / TILE_NODES;  // 0..4; partial handled after

    // double-buffered tile registers (named -> static indexing)
    float4 PA[3], TA[3], XA[8]; int4 BA;
    float4 PB[3], TB[3], XB[8]; int4 BB;

#define LOAD_TILE(t, P, T, B, X)                                          \
    {                                                                     \
        const int g0 = (node0 + (t) * TILE_NODES) / 4 + tid;              \
        const int xb = (node0 + (t) * TILE_NODES) * 2;                    \
        P[0] = p4[g0 * 3 + 0]; P[1] = p4[g0 * 3 + 1]; P[2] = p4[g0 * 3 + 2]; \
        T[0] = t4[g0 * 3 + 0]; T[1] = t4[g0 * 3 + 1]; T[2] = t4[g0 * 3 + 2]; \
        B    = b4[g0];                                                    \
        X[0] = x4[xb + 0 * BLOCK + tid]; X[1] = x4[xb + 1 * BLOCK + tid]; \
        X[2] = x4[xb + 2 * BLOCK + tid]; X[3] = x4[xb + 3 * BLOCK + tid]; \
        X[4] = x4[xb + 4 * BLOCK + tid]; X[5] = x4[xb + 5 * BLOCK + tid]; \
        X[6] = x4[xb + 6 * BLOCK + tid]; X[7] = x4[xb + 7 * BLOCK + tid]; \
    }

#define CONSUME_TILE(P, T, B, X)                                          \
    {                                                                     \
        float4 pa = P[0], pb = P[1], pc = P[2];                           \
        float4 ta = T[0], tb = T[1], tc = T[2];                           \
        float asum[4];                                                    \
        asum[0] = fabsf(pa.x - ta.x) + fabsf(pa.y - ta.y) + fabsf(pa.z - ta.z); \
        asum[1] = fabsf(pa.w - ta.w) + fabsf(pb.x - tb.x) + fabsf(pb.y - tb.y); \
        asum[2] = fabsf(pb.z - tb.z) + fabsf(pb.w - tb.w) + fabsf(pc.x - tc.x); \
        asum[3] = fabsf(pc.y - tc.y) + fabsf(pc.z - tc.z) + fabsf(pc.w - tc.w); \
        int bid[4] = {B.x, B.y, B.z, B.w};                                \
        if (bid[0] == cur_id && bid[3] == cur_id) {                       \
            cur_sum += asum[0] + asum[1] + asum[2] + asum[3];             \
            cur_cnt += 4.f;                                               \
        } else {                                                          \
            _Pragma("unroll")                                             \
            for (int r = 0; r < 4; ++r) {                                 \
                if (bid[r] != cur_id) {                                   \
                    if (cur_id >= 0) {                                    \
                        atomicAdd(&ls[cur_id], cur_sum);                  \
                        atomicAdd(&lc[cur_id], cur_cnt);                  \
                    }                                                     \
                    cur_id = bid[r]; cur_sum = 0.f; cur_cnt = 0.f;        \
                }                                                         \
                cur_sum += asum[r];                                       \
                cur_cnt += 1.f;                                           \
            }                                                             \
        }                                                                 \
        _Pragma("unroll")                                                 \
        for (int v = 0; v < 8; ++v) {                                     \
            const float val = (tid & 1) ? X[v].x : X[v].w;                \
            const float oth = __shfl_xor(val, 1, 64);                     \
            fsum += sqrtf(val * val + oth * oth);                         \
        }                                                                 \
    }

    // ---- fully-unrolled 2-deep pipeline over full tiles ----
    if (ft >= 1) LOAD_TILE(0, PA, TA, BA, XA);
    if (ft >= 2) LOAD_TILE(1, PB, TB, BB, XB);
    if (ft >= 1) CONSUME_TILE(PA, TA, BA, XA);
    if (ft >= 3) LOAD_TILE(2, PA, TA, BA, XA);
    if (ft >= 2) CONSUME_TILE(PB, TB, BB, XB);
    if (ft >= 4) LOAD_TILE(3, PB, TB, BB, XB);
    if (ft >= 3) CONSUME_TILE(PA, TA, BA, XA);
    if (ft >= 4) CONSUME_TILE(PB, TB, BB, XB);

#undef LOAD_TILE
#undef CONSUME_TILE

    // ---- partial tail tile (at most one, last blocks only) ----
    {
        const int tnode0 = node0 + ft * TILE_NODES;
        if (tnode0 < node_end) {
            const int node = tnode0 + tid * 4;
            for (int r = 0; r < 4; ++r) {
                const int nd = node + r;
                if (nd >= n) break;
                float a = fabsf(pred[nd * 3 + 0] - target[nd * 3 + 0])
                        + fabsf(pred[nd * 3 + 1] - target[nd * 3 + 1])
                        + fabsf(pred[nd * 3 + 2] - target[nd * 3 + 2]);
                int b = batch[nd];
                if (b != cur_id) {
                    if (cur_id >= 0) {
                        atomicAdd(&ls[cur_id], cur_sum);
                        atomicAdd(&lc[cur_id], cur_cnt);
                    }
                    cur_id = b; cur_sum = 0.f; cur_cnt = 0.f;
                }
                cur_sum += a;
                cur_cnt += 1.f;
            }
            const int xb  = tnode0 * 2;
            const int nx4 = n * 2;
#pragma unroll
            for (int v = 0; v < 8; ++v) {
                const int idx = xb + v * BLOCK + tid;
                float val = 0.f;
                if (idx < nx4) {
                    float4 xv = x4[idx];
                    val = (tid & 1) ? xv.x : xv.w;
                }
                const float oth = __shfl_xor(val, 1, 64);
                fsum += sqrtf(val * val + oth * oth);   // OOB contributes 0
            }
        }
    }

    // ---- wave-aggregated flush of the final run ----
    {
        const int id0 = __shfl(cur_id, 0, 64);
        if (__all(cur_id == id0)) {
            float s = cur_sum, c = cur_cnt;
#pragma unroll
            for (int off = 32; off > 0; off >>= 1) {
                s += __shfl_xor(s, off, 64);
                c += __shfl_xor(c, off, 64);
            }
            if ((tid & 63) == 0 && id0 >= 0) {
                atomicAdd(&ls[id0], s);
                atomicAdd(&lc[id0], c);
            }
        } else if (cur_id >= 0) {
            atomicAdd(&ls[cur_id], cur_sum);
            atomicAdd(&lc[cur_id], cur_cnt);
        }
    }

    // ---- force: block reduce (each row norm counted by both lanes) ----
    fsum *= 0.5f;
#pragma unroll
    for (int off = 32; off > 0; off >>= 1) fsum += __shfl_down(fsum, off, 64);
    if ((tid & 63) == 0) lf[tid >> 6] = fsum;
    __syncthreads();
    if (tid == 0) {
        atomicAdd(ws_force, lf[0] + lf[1] + lf[2] + lf[3]);
    }

    // ---- flush per-block LDS partials (only the touched id window) ----
    for (int i = b_lo + tid; i <= b_hi; i += BLOCK) {
        float c = lc[i];
        if (c != 0.f) {
            atomicAdd(&ws_sum[i], ls[i]);
            atomicAdd(&ws_cnt[i], c);
        }
    }
}

// ---------------------------------------------------------------------------
// Kernel 2: finalize — mean over graphs of seg_sum/(max(cnt,1)*3), scale.
// ---------------------------------------------------------------------------
__global__ __launch_bounds__(NUM_GRAPHS) void finalize_kernel(
    const float* __restrict__ ws_sum,
    const float* __restrict__ ws_cnt,
    const float* __restrict__ ws_force,
    float* __restrict__ out)
{
    __shared__ float red[NUM_GRAPHS];
    const int t = threadIdx.x;
    red[t] = ws_sum[t] / (fmaxf(ws_cnt[t], 1.0f) * 3.0f);
    __syncthreads();
    for (int s = NUM_GRAPHS / 2; s > 0; s >>= 1) {
        if (t < s) red[t] += red[t + s];
        __syncthreads();
    }
    if (t == 0) {
        const float scale = fmaxf(ws_force[0], 0.1f);
        out[0] = (red[0] / (float)NUM_GRAPHS) * scale * 100.0f;
    }
}

extern "C" void kernel_launch(void* const* d_in, const int* in_sizes, int n_in,
                              void* d_out, int out_size, void* d_ws, size_t ws_size,
                              hipStream_t stream) {
    const float* pred   = (const float*)d_in[0];
    const float* target = (const float*)d_in[1];
    const int*   batch  = (const int*)d_in[2];
    const float* x      = (const float*)d_in[3];
    float* out = (float*)d_out;

    const int n = in_sizes[2];                  // N nodes (batch vector length)

    float* ws_sum   = (float*)d_ws;             // [1024]
    float* ws_cnt   = ws_sum + NUM_GRAPHS;      // [1024]
    float* ws_force = ws_cnt + NUM_GRAPHS;      // [1]

    hipMemsetAsync(d_ws, 0, (2 * NUM_GRAPHS + 1) * sizeof(float), stream);

    const int blocks = (n + CHUNK - 1) / CHUNK;
    mae_seg_kernel<<<blocks, BLOCK, 0, stream>>>(pred, target, batch, x,
                                                 ws_sum, ws_cnt, ws_force, n);
    finalize_kernel<<<1, NUM_GRAPHS, 0, stream>>>(ws_sum, ws_cnt, ws_force, out);
}